// Round 12
// baseline (1327.253 us; speedup 1.0000x reference)
//
#include <hip/hip_runtime.h>
#include <hip/hip_bf16.h>
#include <cstdint>

#define NN 131072      // nodes
#define NE 524288      // directed edges
#define DIM 275        // feature dim
#define DP 288         // padded stride (multiple of 16)
#define NPAN 18        // 288/16 column panels
#define NFEAT 9
#define NVOC 128
#define NLAY 5
#define NPG 64
#define NGRAPH 2048
#define BN_EPS 1e-5f
#define BK 32
#define NEPAD (NE + 3 * NN)   // max padded edge count
#define LDSE 1024             // per-block staged edge indices (128 nodes)

typedef unsigned short u16;
typedef __attribute__((ext_vector_type(8))) short s16x8;
typedef __attribute__((ext_vector_type(4))) float f32x4;

// panel stride in u16 elements: panel-major feature layout X[p][node][16]
#define PS ((size_t)(NN + 1) * 16)

// global_load_lds: linear LDS dest (wave base + lane*16), per-lane global src
#define GLL16(g, l) __builtin_amdgcn_global_load_lds( \
    (const __attribute__((address_space(1))) unsigned int*)(g), \
    (__attribute__((address_space(3))) unsigned int*)(l), 16, 0, 0)

__device__ __forceinline__ float bf2f(u16 u) {
  union { unsigned int i; float f; } x; x.i = ((unsigned int)u) << 16; return x.f;
}
__device__ __forceinline__ u16 f2bf(float f) {
  union { float f; unsigned int i; } x; x.f = f;
  unsigned int r = x.i + 0x7fffu + ((x.i >> 16) & 1u);
  return (u16)(r >> 16);
}

// ---------------- graph preprocessing ----------------

__global__ void hist_kernel(const int* __restrict__ ei, int* __restrict__ cnt) {
  int e = blockIdx.x * 256 + threadIdx.x;
  if (e < NE) atomicAdd(&cnt[ei[NE + e]], 1);
}

__global__ void pad_dinv_kernel(const int* __restrict__ cnt, int* __restrict__ cnt_pad,
                                float* __restrict__ dinv) {
  int v = blockIdx.x * 256 + threadIdx.x;
  if (v < NN) {
    int c = cnt[v];
    cnt_pad[v] = (c + 3) & ~3;
    dinv[v] = rsqrtf(1.0f + (float)c);
  }
}

__global__ void scan_block_kernel(const int* __restrict__ in, int* __restrict__ out_ex,
                                  int* __restrict__ partials) {
  __shared__ int buf[2][1024];
  int t = threadIdx.x;
  int idx = blockIdx.x * 1024 + t;
  int v = in[idx];
  buf[0][t] = v;
  __syncthreads();
  int cur = 0;
  for (int off = 1; off < 1024; off <<= 1) {
    int x = buf[cur][t];
    if (t >= off) x += buf[cur][t - off];
    buf[cur ^ 1][t] = x;
    __syncthreads();
    cur ^= 1;
  }
  out_ex[idx] = buf[cur][t] - v;
  if (t == 1023) partials[blockIdx.x] = buf[cur][t];
}

__global__ void scan_partials_kernel(int* partials) {
  __shared__ int buf[2][128];
  int t = threadIdx.x;
  int v = partials[t];
  buf[0][t] = v;
  __syncthreads();
  int cur = 0;
  for (int off = 1; off < 128; off <<= 1) {
    int x = buf[cur][t];
    if (t >= off) x += buf[cur][t - off];
    buf[cur ^ 1][t] = x;
    __syncthreads();
    cur ^= 1;
  }
  partials[t] = buf[cur][t] - v;
}

__global__ void add_offsets_kernel(int* __restrict__ indptr, const int* __restrict__ partials,
                                   int* __restrict__ cursor, const int* __restrict__ cnt_pad) {
  int i = blockIdx.x * 256 + threadIdx.x;
  if (i < NN) {
    int v = indptr[i] + partials[i >> 10];
    indptr[i] = v;
    cursor[i] = v;
    if (i == NN - 1) indptr[NN] = v + cnt_pad[NN - 1];
  }
}

__global__ void fill_csr_kernel(const int* __restrict__ ei, int* __restrict__ cursor,
                                int* __restrict__ srcs) {
  int e = blockIdx.x * 256 + threadIdx.x;
  if (e < NE) {
    int c = ei[NE + e];
    int p = atomicAdd(&cursor[c], 1);
    srcs[p] = ei[e];
  }
}

// pad slots point at the all-zeros row NN
__global__ void pad_fill_kernel(const int* __restrict__ cursor, const int* __restrict__ indptr,
                                int* __restrict__ srcs) {
  int v = blockIdx.x * 256 + threadIdx.x;
  if (v < NN) {
    int pe = indptr[v + 1];
    for (int p = cursor[v]; p < pe; ++p) srcs[p] = NN;
  }
}

// zero the phantom row NN of every panel in both feature buffers
__global__ void zrow_kernel(u16* __restrict__ P, u16* __restrict__ Q) {
  int i = threadIdx.x;
  if (i < NPAN * 16) {
    size_t off = (size_t)(i >> 4) * PS + (size_t)NN * 16 + (i & 15);
    P[off] = 0;
    Q[off] = 0;
  }
}

// Pad + PRE-SWIZZLE weights (row-major, unchanged from r11): within each 64B
// K-group of row j, 16B chunks permuted by s(j)=(j&3)^((j>>2)&3) so that
// global_load_lds (linear dest) + XOR fragment reads are conflict-free.
__global__ void wpad_kernel(const float* __restrict__ convW, const float* __restrict__ postW,
                            u16* __restrict__ Wp) {
  int i = blockIdx.x * 256 + threadIdx.x;
  const int total = 6 * 320 * DP;
  if (i >= total) return;
  int k = i % DP;
  int r = i / DP;
  int j = r % 320;
  int m = r / 320;
  float val = 0.f;
  if (j < DIM && k < DIM)
    val = (m < 5) ? convW[((size_t)m * DIM + j) * DIM + k] : postW[(size_t)j * DIM + k];
  int s = (j & 3) ^ ((j >> 2) & 3);
  int kout = (k & ~24) | (((((k >> 3) & 3)) ^ s) << 3);
  Wp[(size_t)r * DP + kout] = f2bf(val);
}

// ---------------- atom encoder (panel-major output) ----------------

__global__ void embed_kernel(const int* __restrict__ xa, const float* __restrict__ emb,
                             u16* __restrict__ P) {
  int n = blockIdx.x;
  int idx[NFEAT];
#pragma unroll
  for (int f = 0; f < NFEAT; ++f) idx[f] = xa[n * NFEAT + f];
  for (int d = threadIdx.x; d < DP; d += 128) {
    float s = 0.f;
    if (d < DIM) {
#pragma unroll
      for (int f = 0; f < NFEAT; ++f) s += emb[((size_t)f * NVOC + idx[f]) * DIM + d];
    }
    P[(size_t)(d >> 4) * PS + (size_t)n * 16 + (d & 15)] = f2bf(s);
  }
}

// ---------------- MFMA GEMM v6: panel-major A/C, gll B, dbuf, 1 barrier ----------------
// Block = 64 rows x 288 cols, 4 waves 2Mx2N, wave 32x144, acc 18 f32x4.

__device__ __forceinline__ uint4 xform8s(uint4 r, const float* __restrict__ sc,
                                         const float* __restrict__ sh, int k) {
  union { uint4 u; u16 h[8]; } in, out;
  in.u = r;
#pragma unroll
  for (int j = 0; j < 8; ++j) {
    float x = fmaf(bf2f(in.h[j]), sc[k + j], sh[k + j]);
    out.h[j] = f2bf(fmaxf(x, 0.f));
  }
  return out.u;
}

__launch_bounds__(256)
__global__ void gemm_kernel(const u16* __restrict__ A, const u16* __restrict__ Wq,
                            u16* __restrict__ C,
                            const float* __restrict__ bn_sum, const float* __restrict__ bn_sq,
                            const float* __restrict__ gamma, const float* __restrict__ beta,
                            const float* __restrict__ rowscale, const float* __restrict__ colbias) {
  __shared__ __align__(16) u16 Asl[2][64 * BK];     // 2 x 4 KB
  __shared__ __align__(16) u16 Bsl[2][288 * BK];    // 2 x 18 KB
  __shared__ float scs[DP], shs[DP];
  const int tid = threadIdx.x, lane = tid & 63, wv = tid >> 6;
  const int wm = wv & 1, wn = wv >> 1;
  const int row0 = blockIdx.x * 64;
  const bool bn = (bn_sum != nullptr);

  // fused bn_finalize
  for (int d = tid; d < DP; d += 256) {
    float sc = 1.f, sh = 0.f;
    if (bn) {
      if (d < DIM) {
        const float invN = 1.0f / (float)NN;
        float mu = bn_sum[d] * invN;
        float var = bn_sq[d] * invN - mu * mu;
        float rstd = rsqrtf(var + BN_EPS);
        sc = gamma[d] * rstd;
        sh = fmaf(-mu, sc, beta[d]);
      } else {
        sc = 0.f; sh = 0.f;
      }
    }
    scs[d] = sc; shs[d] = sh;
  }

  // A staging: thread t covers row t>>2, 16B chunk t&3 of the 32-col K-step.
  // Panel-major source: cols s*32+schk*8 -> panel 2s+(schk>>1), elem (schk&1)*8
  const int srow = tid >> 2, schk = tid & 3;
  const int swz = ((schk ^ (srow & 3) ^ ((srow >> 2) & 3)) << 3);
  const int awoff = srow * BK + swz;
  const u16* ag = A + (size_t)(schk >> 1) * PS + (size_t)(row0 + srow) * 16 + (schk & 1) * 8;
  // B staging (gll): instr i covers rows i*16..i*16+15; lane l -> row i*16+(l>>2), pos l&3
  const int grow = lane >> 2, gchk = (lane & 3) * 8;

  // fragment read offsets
  const int fr = lane & 15, fs = lane >> 4;
  int aoff[2], boff[9];
#pragma unroll
  for (int i = 0; i < 2; ++i) {
    int r = wm * 32 + i * 16 + fr;
    aoff[i] = r * BK + ((fs ^ (r & 3) ^ ((r >> 2) & 3)) << 3);
  }
#pragma unroll
  for (int j = 0; j < 9; ++j) {
    int r = wn * 144 + j * 16 + fr;
    boff[j] = r * BK + ((fs ^ (r & 3) ^ ((r >> 2) & 3)) << 3);
  }

  // prologue: issue B0 gll, load A0, finalize scs
  for (int i = wv; i < 18; i += 4)
    GLL16(Wq + (size_t)(i * 16 + grow) * DP + gchk, &Bsl[0][i * 512]);
  uint4 ra = *(const uint4*)(ag);
  __syncthreads();               // scs/shs ready; B0 gll drained by waitcnt
  if (bn) ra = xform8s(ra, scs, shs, schk * 8);
  *(uint4*)&Asl[0][awoff] = ra;
  __syncthreads();

  f32x4 acc0[9], acc1[9];
#pragma unroll
  for (int j = 0; j < 9; ++j) {
    acc0[j] = (f32x4){0.f, 0.f, 0.f, 0.f};
    acc1[j] = (f32x4){0.f, 0.f, 0.f, 0.f};
  }

#pragma unroll 1
  for (int s = 0; s < 9; ++s) {
    const int cur = s & 1;
    const bool more = (s < 8);
    uint4 na;
    if (more) {   // prefetch s+1 into other buffer; lands under MFMA
      int k = (s + 1) * BK;
      for (int i = wv; i < 18; i += 4)
        GLL16(Wq + (size_t)(i * 16 + grow) * DP + k + gchk, &Bsl[cur ^ 1][i * 512]);
      na = *(const uint4*)(ag + (size_t)(2 * (s + 1)) * PS);
    }
    s16x8 af0 = *(const s16x8*)&Asl[cur][aoff[0]];
    s16x8 af1 = *(const s16x8*)&Asl[cur][aoff[1]];
#pragma unroll
    for (int j = 0; j < 9; ++j) {
      s16x8 bf = *(const s16x8*)&Bsl[cur][boff[j]];
      acc0[j] = __builtin_amdgcn_mfma_f32_16x16x32_bf16(af0, bf, acc0[j], 0, 0, 0);
      acc1[j] = __builtin_amdgcn_mfma_f32_16x16x32_bf16(af1, bf, acc1[j], 0, 0, 0);
    }
    if (more) {
      if (bn) na = xform8s(na, scs, shs, (s + 1) * BK + schk * 8);
      *(uint4*)&Asl[cur ^ 1][awoff] = na;
    }
    __syncthreads();
  }

  // epilogue: row = wm*32+i*16+fs*4+r, col = wn*144+j*16+fr -> panel wn*9+j
#pragma unroll
  for (int i = 0; i < 2; ++i) {
    int gr0 = row0 + wm * 32 + i * 16 + fs * 4;
    float rs[4];
#pragma unroll
    for (int r = 0; r < 4; ++r) rs[r] = rowscale ? rowscale[gr0 + r] : 1.f;
#pragma unroll
    for (int j = 0; j < 9; ++j) {
      f32x4 av = i ? acc1[j] : acc0[j];
      int gc = wn * 144 + j * 16 + fr;
      float cb = (colbias && gc < DIM) ? colbias[gc] : 0.f;
      u16* cp = C + (size_t)(wn * 9 + j) * PS + (size_t)gr0 * 16 + fr;
#pragma unroll
      for (int r = 0; r < 4; ++r) {
        u16 o = (gc < DIM) ? f2bf(fmaf(av[r], rs[r], cb)) : (u16)0;
        cp[(size_t)r * 16] = o;
      }
    }
  }
}

// ---------------- SpMM v7: panel-major, L2-resident gathers ----------------
// Grid = NPAN * (NN/128), panel-major dispatch: within one panel phase every
// edge gathers 32B from a 4.2MB panel (20x touch density per 128B line ->
// L2 hits after first touch). Wave = 32 nodes as pair-interleave (r6 shape):
// lane = (node-slot l>>3, col-pair (l&7)*2); 8 gathers in flight.

__launch_bounds__(256)
__global__ void spmm_kernel(const u16* __restrict__ X, u16* __restrict__ Y,
                            const int* __restrict__ indptr, const int* __restrict__ srcs,
                            const float* __restrict__ dinv, const float* __restrict__ bias,
                            float* __restrict__ bn_sum, float* __restrict__ bn_sq) {
  __shared__ int sptr[129];
  __shared__ __align__(16) int sidx[LDSE];
  __shared__ float ls[16], lq[16];
  const int tid = threadIdx.x;
  const int p = blockIdx.x >> 10;          // panel (NN/128 = 1024 groups)
  const int g = blockIdx.x & 1023;
  const int vb = g * 128;
  const u16* Xp = X + (size_t)p * PS;
  u16* Yp = Y + (size_t)p * PS;
  if (tid < 129) sptr[tid] = indptr[vb + tid];
  if (tid < 16) { ls[tid] = 0.f; lq[tid] = 0.f; }
  __syncthreads();
  int ebase = sptr[0];
  int ecnt = sptr[128] - ebase;
  const int* ip;
  if (ecnt <= LDSE) {
    for (int i = tid; i < ecnt; i += 256) sidx[i] = srcs[ebase + i];
    ip = sidx;
  } else {
    ip = srcs + ebase;
  }
  __syncthreads();

  const int lane = tid & 63, wv = tid >> 6;
  const int slot = lane >> 3;
  const int cp = (lane & 7) << 1;          // col pair within panel
  const int gc = p * 16 + cp;
  float b0 = (gc < DIM) ? bias[gc] : 0.f;
  float b1 = (gc + 1 < DIM) ? bias[gc + 1] : 0.f;
  float s0 = 0.f, s1 = 0.f, q0 = 0.f, q1 = 0.f;

  for (int h = 0; h < 2; ++h) {
    int nlA = wv * 32 + h * 16 + slot;
    int nlB = nlA + 8;
    int nsA = vb + nlA, nsB = vb + nlB;
    int ebA = sptr[nlA] - ebase, neA = sptr[nlA + 1] - sptr[nlA];
    int ebB = sptr[nlB] - ebase, neB = sptr[nlB + 1] - sptr[nlB];
    int nemax = neA > neB ? neA : neB;
    unsigned mA = *(const unsigned*)(Xp + (size_t)nsA * 16 + cp);
    unsigned mB = *(const unsigned*)(Xp + (size_t)nsB * 16 + cp);
    float a0 = bf2f((u16)mA), a1 = bf2f((u16)(mA >> 16));
    float c0 = bf2f((u16)mB), c1 = bf2f((u16)(mB >> 16));
    for (int e = 0; e < nemax; e += 4) {
      bool aA = e < neA, aB = e < neB;     // padded degs are multiples of 4
      int oA = aA ? ebA + e : 0;
      int oB = aB ? ebB + e : 0;
      int ia[4], ib[4];
#pragma unroll
      for (int j = 0; j < 4; ++j) {
        int va = ip[oA + j], vx = ip[oB + j];
        ia[j] = aA ? va : NN;
        ib[j] = aB ? vx : NN;
      }
      unsigned ga[4], gb[4];
#pragma unroll
      for (int j = 0; j < 4; ++j) ga[j] = *(const unsigned*)(Xp + (size_t)ia[j] * 16 + cp);
#pragma unroll
      for (int j = 0; j < 4; ++j) gb[j] = *(const unsigned*)(Xp + (size_t)ib[j] * 16 + cp);
#pragma unroll
      for (int j = 0; j < 4; ++j) {
        a0 += bf2f((u16)ga[j]); a1 += bf2f((u16)(ga[j] >> 16));
        c0 += bf2f((u16)gb[j]); c1 += bf2f((u16)(gb[j] >> 16));
      }
    }
    float dvA = dinv[nsA], dvB = dinv[nsB];
    float yA0 = fmaf(dvA, a0, b0), yA1 = fmaf(dvA, a1, b1);
    float yB0 = fmaf(dvB, c0, b0), yB1 = fmaf(dvB, c1, b1);
    s0 += yA0 + yB0; q0 += yA0 * yA0 + yB0 * yB0;
    s1 += yA1 + yB1; q1 += yA1 * yA1 + yB1 * yB1;
    *(unsigned*)(Yp + (size_t)nsA * 16 + cp) =
        (unsigned)f2bf(yA0) | ((unsigned)f2bf(yA1) << 16);
    *(unsigned*)(Yp + (size_t)nsB * 16 + cp) =
        (unsigned)f2bf(yB0) | ((unsigned)f2bf(yB1) << 16);
  }

  atomicAdd(&ls[cp], s0); atomicAdd(&ls[cp + 1], s1);
  atomicAdd(&lq[cp], q0); atomicAdd(&lq[cp + 1], q1);
  __syncthreads();
  if (tid < 16) {
    atomicAdd(&bn_sum[p * 16 + tid], ls[tid]);
    atomicAdd(&bn_sq[p * 16 + tid], lq[tid]);
  }
}

// ---------------- MFMA Gram decode (panel-major input) ----------------

__launch_bounds__(256)
__global__ void decode_kernel(const u16* __restrict__ H, float* __restrict__ out) {
  __shared__ __align__(16) u16 tile[4][2][NPG * BK];
  int tid = threadIdx.x, lane = tid & 63, wv = tid >> 6;
  int g = blockIdx.x * 4 + wv;
  const int ssl = lane & 3;
  int soff[4];
  const u16* sg[4];
#pragma unroll
  for (int i = 0; i < 4; ++i) {
    int r = (lane >> 2) + i * 16;
    soff[i] = r * BK + ((ssl ^ (r & 3) ^ ((r >> 2) & 3)) << 3);
    // cols ssl*8 + s*32 -> panel 2s+(ssl>>1), elem (ssl&1)*8; row = g*64+r
    sg[i] = H + (size_t)(ssl >> 1) * PS + (size_t)(g * NPG + r) * 16 + (ssl & 1) * 8;
  }
  const int fr = lane & 15, fs = lane >> 4;
  const int fswz = ((fs ^ (fr & 3) ^ ((fr >> 2) & 3)) << 3);
  int foff[4];
#pragma unroll
  for (int i = 0; i < 4; ++i) foff[i] = (i * 16 + fr) * BK + fswz;

  u16* t0 = tile[wv][0];
  u16* t1 = tile[wv][1];
  uint4 rg[4];
#pragma unroll
  for (int i = 0; i < 4; ++i) rg[i] = *(const uint4*)(sg[i]);
#pragma unroll
  for (int i = 0; i < 4; ++i) *(uint4*)&t0[soff[i]] = rg[i];

  f32x4 acc[4][4];
#pragma unroll
  for (int i = 0; i < 4; ++i)
#pragma unroll
    for (int j = 0; j < 4; ++j) acc[i][j] = (f32x4){0.f, 0.f, 0.f, 0.f};

  for (int s = 0; s < DP / BK; ++s) {
    u16* cur = (s & 1) ? t1 : t0;
    u16* nxt = (s & 1) ? t0 : t1;
    const bool more = (s < DP / BK - 1);
    if (more) {
#pragma unroll
      for (int i = 0; i < 4; ++i)
        rg[i] = *(const uint4*)(sg[i] + (size_t)(2 * (s + 1)) * PS);
    }
    s16x8 af[4];
#pragma unroll
    for (int i = 0; i < 4; ++i) af[i] = *(const s16x8*)&cur[foff[i]];
#pragma unroll
    for (int i = 0; i < 4; ++i)
#pragma unroll
      for (int j = 0; j < 4; ++j)
        acc[i][j] = __builtin_amdgcn_mfma_f32_16x16x32_bf16(af[i], af[j], acc[i][j], 0, 0, 0);
    if (more) {
#pragma unroll
      for (int i = 0; i < 4; ++i) *(uint4*)&nxt[soff[i]] = rg[i];
    }
  }
  float* og = out + (size_t)g * NPG * NPG;
#pragma unroll
  for (int i = 0; i < 4; ++i) {
    int m0 = i * 16 + fs * 4;
#pragma unroll
    for (int j = 0; j < 4; ++j) {
      int n = j * 16 + fr;
#pragma unroll
      for (int r = 0; r < 4; ++r) og[(m0 + r) * NPG + n] = acc[i][j][r];
    }
  }
}

// ---------------- launch ----------------

extern "C" void kernel_launch(void* const* d_in, const int* in_sizes, int n_in,
                              void* d_out, int out_size, void* d_ws, size_t ws_size,
                              hipStream_t stream) {
  const int* xa = (const int*)d_in[0];
  const int* ei = (const int*)d_in[1];
  const float* emb = (const float*)d_in[2];
  const float* convW = (const float*)d_in[3];
  const float* convB = (const float*)d_in[4];
  const float* gamma = (const float*)d_in[5];
  const float* beta = (const float*)d_in[6];
  const float* postW = (const float*)d_in[7];
  const float* postB = (const float*)d_in[8];
  float* out = (float*)d_out;

  char* w = (char*)d_ws;
  u16* P = (u16*)w;          w += (size_t)(NN + 1) * DP * sizeof(u16);
  u16* Q = (u16*)w;          w += (size_t)(NN + 1) * DP * sizeof(u16);
  u16* Wp = (u16*)w;         w += (size_t)6 * 320 * DP * sizeof(u16);
  float* dinv = (float*)w;   w += (size_t)NN * sizeof(float);
  int* cnt = (int*)w;        w += (size_t)NN * sizeof(int);
  int* cnt_pad = (int*)w;    w += (size_t)NN * sizeof(int);
  int* indptr = (int*)w;     w += (size_t)(NN + 64) * sizeof(int);
  int* cursor = (int*)w;     w += (size_t)NN * sizeof(int);
  int* srcs = (int*)w;       w += (size_t)NEPAD * sizeof(int);
  int* partials = (int*)w;   w += 256 * sizeof(int);
  float* bnstats = (float*)w; w += (size_t)NLAY * 2 * DP * sizeof(float);

  size_t need = (size_t)(w - (char*)d_ws);
  if (ws_size < need) return;

  hipMemsetAsync(cnt, 0, (size_t)NN * sizeof(int), stream);
  hipMemsetAsync(bnstats, 0, (size_t)NLAY * 2 * DP * sizeof(float), stream);
  hist_kernel<<<NE / 256, 256, 0, stream>>>(ei, cnt);
  pad_dinv_kernel<<<NN / 256, 256, 0, stream>>>(cnt, cnt_pad, dinv);
  scan_block_kernel<<<NN / 1024, 1024, 0, stream>>>(cnt_pad, indptr, partials);
  scan_partials_kernel<<<1, 128, 0, stream>>>(partials);
  add_offsets_kernel<<<NN / 256, 256, 0, stream>>>(indptr, partials, cursor, cnt_pad);
  fill_csr_kernel<<<NE / 256, 256, 0, stream>>>(ei, cursor, srcs);
  pad_fill_kernel<<<NN / 256, 256, 0, stream>>>(cursor, indptr, srcs);
  wpad_kernel<<<(6 * 320 * DP + 255) / 256, 256, 0, stream>>>(convW, postW, Wp);
  embed_kernel<<<NN, 128, 0, stream>>>(xa, emb, P);
  zrow_kernel<<<1, 288, 0, stream>>>(P, Q);

  for (int l = 0; l < NLAY; ++l) {
    const float* bs = l ? bnstats + (size_t)(l - 1) * 2 * DP : nullptr;
    gemm_kernel<<<NN / 64, 256, 0, stream>>>(
        P, Wp + (size_t)l * 320 * DP, Q,
        bs, bs ? bs + DP : nullptr,
        l ? gamma + (size_t)(l - 1) * DIM : nullptr,
        l ? beta + (size_t)(l - 1) * DIM : nullptr,
        dinv, nullptr);
    spmm_kernel<<<NPAN * (NN / 128), 256, 0, stream>>>(
        Q, P, indptr, srcs, dinv, convB + (size_t)l * DIM,
        bnstats + (size_t)l * 2 * DP, bnstats + (size_t)l * 2 * DP + DP);
  }

  const float* bs5 = bnstats + (size_t)4 * 2 * DP;
  gemm_kernel<<<NN / 64, 256, 0, stream>>>(
      P, Wp + (size_t)5 * 320 * DP, Q, bs5, bs5 + DP,
      gamma + (size_t)4 * DIM, beta + (size_t)4 * DIM, nullptr, postB);

  decode_kernel<<<NGRAPH / 4, 256, 0, stream>>>(Q, out);
}

// Round 13
// 973.998 us; speedup vs baseline: 1.3627x; 1.3627x over previous
//
#include <hip/hip_runtime.h>
#include <hip/hip_bf16.h>
#include <cstdint>

#define NN 131072      // nodes
#define NE 524288      // directed edges
#define DIM 275        // feature dim
#define DP 288         // padded stride (multiple of 16)
#define NFEAT 9
#define NVOC 128
#define NLAY 5
#define NPG 64
#define NGRAPH 2048
#define BN_EPS 1e-5f
#define BK 32
#define NEPAD (NE + 3 * NN)   // max padded edge count
#define LDSE 1536             // per-block staged edge indices (64 nodes)
#define WELEM (18 * 9 * 64 * 8)   // frag-major weight elems per matrix

typedef unsigned short u16;
typedef __attribute__((ext_vector_type(8))) short s16x8;
typedef __attribute__((ext_vector_type(4))) float f32x4;

__device__ __forceinline__ float bf2f(u16 u) {
  union { unsigned int i; float f; } x; x.i = ((unsigned int)u) << 16; return x.f;
}
__device__ __forceinline__ u16 f2bf(float f) {
  union { float f; unsigned int i; } x; x.f = f;
  unsigned int r = x.i + 0x7fffu + ((x.i >> 16) & 1u);
  return (u16)(r >> 16);
}
__device__ __forceinline__ void acc4(float* a, uint2 m) {
  a[0] += bf2f((u16)m.x); a[1] += bf2f((u16)(m.x >> 16));
  a[2] += bf2f((u16)m.y); a[3] += bf2f((u16)(m.y >> 16));
}

// ---------------- graph preprocessing ----------------

__global__ void hist_kernel(const int* __restrict__ ei, int* __restrict__ cnt) {
  int e = blockIdx.x * 256 + threadIdx.x;
  if (e < NE) atomicAdd(&cnt[ei[NE + e]], 1);
}

__global__ void pad_dinv_kernel(const int* __restrict__ cnt, int* __restrict__ cnt_pad,
                                float* __restrict__ dinv) {
  int v = blockIdx.x * 256 + threadIdx.x;
  if (v < NN) {
    int c = cnt[v];
    cnt_pad[v] = (c + 3) & ~3;
    dinv[v] = rsqrtf(1.0f + (float)c);
  }
}

__global__ void scan_block_kernel(const int* __restrict__ in, int* __restrict__ out_ex,
                                  int* __restrict__ partials) {
  __shared__ int buf[2][1024];
  int t = threadIdx.x;
  int idx = blockIdx.x * 1024 + t;
  int v = in[idx];
  buf[0][t] = v;
  __syncthreads();
  int cur = 0;
  for (int off = 1; off < 1024; off <<= 1) {
    int x = buf[cur][t];
    if (t >= off) x += buf[cur][t - off];
    buf[cur ^ 1][t] = x;
    __syncthreads();
    cur ^= 1;
  }
  out_ex[idx] = buf[cur][t] - v;
  if (t == 1023) partials[blockIdx.x] = buf[cur][t];
}

__global__ void scan_partials_kernel(int* partials) {
  __shared__ int buf[2][128];
  int t = threadIdx.x;
  int v = partials[t];
  buf[0][t] = v;
  __syncthreads();
  int cur = 0;
  for (int off = 1; off < 128; off <<= 1) {
    int x = buf[cur][t];
    if (t >= off) x += buf[cur][t - off];
    buf[cur ^ 1][t] = x;
    __syncthreads();
    cur ^= 1;
  }
  partials[t] = buf[cur][t] - v;
}

__global__ void add_offsets_kernel(int* __restrict__ indptr, const int* __restrict__ partials,
                                   int* __restrict__ cursor, const int* __restrict__ cnt_pad) {
  int i = blockIdx.x * 256 + threadIdx.x;
  if (i < NN) {
    int v = indptr[i] + partials[i >> 10];
    indptr[i] = v;
    cursor[i] = v;
    if (i == NN - 1) indptr[NN] = v + cnt_pad[NN - 1];
  }
}

__global__ void fill_csr_kernel(const int* __restrict__ ei, int* __restrict__ cursor,
                                int* __restrict__ srcs) {
  int e = blockIdx.x * 256 + threadIdx.x;
  if (e < NE) {
    int c = ei[NE + e];
    int p = atomicAdd(&cursor[c], 1);
    srcs[p] = ei[e];
  }
}

// pad slots point at the all-zeros row NN
__global__ void pad_fill_kernel(const int* __restrict__ cursor, const int* __restrict__ indptr,
                                int* __restrict__ srcs) {
  int v = blockIdx.x * 256 + threadIdx.x;
  if (v < NN) {
    int pe = indptr[v + 1];
    for (int p = cursor[v]; p < pe; ++p) srcs[p] = NN;
  }
}

__global__ void zrow_kernel(u16* __restrict__ P, u16* __restrict__ Q) {
  int i = threadIdx.x;
  if (i < DP) {
    P[(size_t)NN * DP + i] = 0;
    Q[(size_t)NN * DP + i] = 0;
  }
}

// Frag-major weight layout: W'[m][jt][s][lane][e] = W[m][col][k],
// col = jt*16 + (lane&15), k = s*32 + (lane>>4)*8 + e. Each B-fragment of
// gemm is then ONE coalesced 1KB global load (L2-resident), no LDS needed.
__global__ void wpad_kernel(const float* __restrict__ convW, const float* __restrict__ postW,
                            u16* __restrict__ Wr) {
  int i = blockIdx.x * 256 + threadIdx.x;
  const int total = 6 * WELEM;
  if (i >= total) return;
  int e = i & 7;
  int l = (i >> 3) & 63;
  int rest = i >> 9;
  int s = rest % 9; rest /= 9;
  int jt = rest % 18;
  int m = rest / 18;
  int col = jt * 16 + (l & 15);
  int k = s * 32 + (l >> 4) * 8 + e;
  float val = 0.f;
  if (col < DIM && k < DIM)
    val = (m < 5) ? convW[((size_t)m * DIM + col) * DIM + k] : postW[(size_t)col * DIM + k];
  Wr[i] = f2bf(val);
}

// ---------------- atom encoder ----------------

__global__ void embed_kernel(const int* __restrict__ xa, const float* __restrict__ emb,
                             u16* __restrict__ P) {
  int n = blockIdx.x;
  int idx[NFEAT];
#pragma unroll
  for (int f = 0; f < NFEAT; ++f) idx[f] = xa[n * NFEAT + f];
  for (int d = threadIdx.x; d < DP; d += 128) {
    float s = 0.f;
    if (d < DIM) {
#pragma unroll
      for (int f = 0; f < NFEAT; ++f) s += emb[((size_t)f * NVOC + idx[f]) * DIM + d];
    }
    P[(size_t)n * DP + d] = f2bf(s);
  }
}

// ---------------- MFMA GEMM v7: barrier-free, direct-frag B ----------------
// Block 64 rows x 288 cols, 4 waves 2Mx2N, wave 32x144 (2 A-frags x 9 B-frags).
// B: one coalesced uint4 per frag from frag-major Wr (L2-hot) -> no B-LDS.
// A: wave-private 2KB dbuf LDS (global 64B-segment loads, BN+ReLU in reg,
// XOR-swizzled write, frag read) -> no barriers in the K-loop at all.

__launch_bounds__(256, 3)
__global__ void gemm_kernel(const u16* __restrict__ A, const u16* __restrict__ Wr,
                            u16* __restrict__ C,
                            const float* __restrict__ bn_sum, const float* __restrict__ bn_sq,
                            const float* __restrict__ gamma, const float* __restrict__ beta,
                            const float* __restrict__ rowscale, const float* __restrict__ colbias) {
  __shared__ __align__(16) u16 Awp[4][2][32 * 32];   // per-wave A dbuf, 16KB
  __shared__ float scs[DP], shs[DP];
  const int tid = threadIdx.x, lane = tid & 63, wv = tid >> 6;
  const int wm = wv & 1, wn = wv >> 1;
  const int row0 = blockIdx.x * 64;
  const bool bn = (bn_sum != nullptr);

  // fused bn_finalize into block-shared scale/shift table
  for (int d = tid; d < DP; d += 256) {
    float sc = 1.f, sh = 0.f;
    if (bn) {
      if (d < DIM) {
        const float invN = 1.0f / (float)NN;
        float mu = bn_sum[d] * invN;
        float var = bn_sq[d] * invN - mu * mu;
        float rstd = rsqrtf(var + BN_EPS);
        sc = gamma[d] * rstd;
        sh = fmaf(-mu, sc, beta[d]);
      } else {
        sc = 0.f; sh = 0.f;   // pad cols: relu(0*x+0)=0
      }
    }
    scs[d] = sc; shs[d] = sh;
  }

  // A staging: lane l covers rows r = (l>>2) and 16+(l>>2), 16B chunk l&3
  const int sr0 = lane >> 2, sch = lane & 3;
  const int wp0 = sr0 * 32 + ((sch ^ (sr0 & 3)) << 3);           // row sr0
  const int sr1 = 16 + sr0;
  const int wp1 = sr1 * 32 + ((sch ^ (sr1 & 3)) << 3);           // row sr1
  const u16* ag = A + (size_t)(row0 + wm * 32) * DP + sch * 8;
  const u16* ag0 = ag + (size_t)sr0 * DP;
  const u16* ag1 = ag + (size_t)sr1 * DP;
  // fragment reads
  const int fr = lane & 15, fs = lane >> 4;
  const int ar0 = fr, ar1 = 16 + fr;
  const int af0o = ar0 * 32 + (((fs) ^ (ar0 & 3)) << 3);
  const int af1o = ar1 * 32 + (((fs) ^ (ar1 & 3)) << 3);
  // B frag pointers: frag (jt = wn*9+j, s) at ((jt*9+s)*64 + lane)*8
  const u16* bg = Wr + ((size_t)(wn * 9) * 9 * 64 + lane) * 8;

  __syncthreads();    // scs/shs ready (only barrier in the kernel)

  // prologue: stage A(0) into buf 0
  {
    uint4 a0 = *(const uint4*)(ag0);
    uint4 a1 = *(const uint4*)(ag1);
    if (bn) {
      int k = sch * 8;
      float4 c0 = *(const float4*)&scs[k], c1 = *(const float4*)&scs[k + 4];
      float4 h0 = *(const float4*)&shs[k], h1 = *(const float4*)&shs[k + 4];
      union { uint4 u; u16 h[8]; } in0, in1, o0, o1;
      in0.u = a0; in1.u = a1;
      const float* cc = (const float*)&c0;  // c0,c1 contiguous? use per-elem:
      float sc[8] = {c0.x, c0.y, c0.z, c0.w, c1.x, c1.y, c1.z, c1.w};
      float sh[8] = {h0.x, h0.y, h0.z, h0.w, h1.x, h1.y, h1.z, h1.w};
      (void)cc;
#pragma unroll
      for (int j = 0; j < 8; ++j) {
        o0.h[j] = f2bf(fmaxf(fmaf(bf2f(in0.h[j]), sc[j], sh[j]), 0.f));
        o1.h[j] = f2bf(fmaxf(fmaf(bf2f(in1.h[j]), sc[j], sh[j]), 0.f));
      }
      a0 = o0.u; a1 = o1.u;
    }
    *(uint4*)&Awp[wv][0][wp0] = a0;
    *(uint4*)&Awp[wv][0][wp1] = a1;
  }

  f32x4 acc0[9], acc1[9];
#pragma unroll
  for (int j = 0; j < 9; ++j) {
    acc0[j] = (f32x4){0.f, 0.f, 0.f, 0.f};
    acc1[j] = (f32x4){0.f, 0.f, 0.f, 0.f};
  }

#pragma unroll 1
  for (int s = 0; s < 9; ++s) {
    const int cur = s & 1;
    const bool more = (s < 8);
    // B frags for step s: 9 coalesced 1KB loads from L2-hot Wr
    uint4 braw[9];
#pragma unroll
    for (int j = 0; j < 9; ++j)
      braw[j] = *(const uint4*)(bg + (size_t)(j * 9 + s) * 64 * 8);
    // A(s+1) global prefetch
    uint4 na0, na1;
    if (more) {
      int k = (s + 1) * BK;
      na0 = *(const uint4*)(ag0 + k);
      na1 = *(const uint4*)(ag1 + k);
    }
    // A frags for step s from wave-private LDS
    s16x8 af0 = *(const s16x8*)&Awp[wv][cur][af0o];
    s16x8 af1 = *(const s16x8*)&Awp[wv][cur][af1o];
#pragma unroll
    for (int j = 0; j < 9; ++j) {
      union { uint4 u; s16x8 v; } cb; cb.u = braw[j];
      acc0[j] = __builtin_amdgcn_mfma_f32_16x16x32_bf16(af0, cb.v, acc0[j], 0, 0, 0);
      acc1[j] = __builtin_amdgcn_mfma_f32_16x16x32_bf16(af1, cb.v, acc1[j], 0, 0, 0);
    }
    if (more) {
      if (bn) {
        int k = (s + 1) * BK + sch * 8;
        float4 c0 = *(const float4*)&scs[k], c1 = *(const float4*)&scs[k + 4];
        float4 h0 = *(const float4*)&shs[k], h1 = *(const float4*)&shs[k + 4];
        float sc[8] = {c0.x, c0.y, c0.z, c0.w, c1.x, c1.y, c1.z, c1.w};
        float sh[8] = {h0.x, h0.y, h0.z, h0.w, h1.x, h1.y, h1.z, h1.w};
        union { uint4 u; u16 h[8]; } in0, in1, o0, o1;
        in0.u = na0; in1.u = na1;
#pragma unroll
        for (int j = 0; j < 8; ++j) {
          o0.h[j] = f2bf(fmaxf(fmaf(bf2f(in0.h[j]), sc[j], sh[j]), 0.f));
          o1.h[j] = f2bf(fmaxf(fmaf(bf2f(in1.h[j]), sc[j], sh[j]), 0.f));
        }
        na0 = o0.u; na1 = o1.u;
      }
      *(uint4*)&Awp[wv][cur ^ 1][wp0] = na0;
      *(uint4*)&Awp[wv][cur ^ 1][wp1] = na1;
    }
  }

  // epilogue: D row = wm*32 + i*16 + fs*4 + r, col = wn*144 + j*16 + fr
#pragma unroll
  for (int i = 0; i < 2; ++i) {
    int gr0 = row0 + wm * 32 + i * 16 + fs * 4;
    float rs[4];
#pragma unroll
    for (int r = 0; r < 4; ++r) rs[r] = rowscale ? rowscale[gr0 + r] : 1.f;
#pragma unroll
    for (int j = 0; j < 9; ++j) {
      f32x4 av = i ? acc1[j] : acc0[j];
      int gc = wn * 144 + j * 16 + fr;
      float cb = (colbias && gc < DIM) ? colbias[gc] : 0.f;
#pragma unroll
      for (int r = 0; r < 4; ++r) {
        u16 o = (gc < DIM) ? f2bf(fmaf(av[r], rs[r], cb)) : (u16)0;
        C[(size_t)(gr0 + r) * DP + gc] = o;
      }
    }
  }
}

// ---------------- SpMM (r11 v6, 103us): LDS idx + pair-interleave, merged c1 ----------------

__launch_bounds__(256)
__global__ void spmm_kernel(const u16* __restrict__ X, u16* __restrict__ Y,
                            const int* __restrict__ indptr, const int* __restrict__ srcs,
                            const float* __restrict__ dinv, const float* __restrict__ bias,
                            float* __restrict__ bn_sum, float* __restrict__ bn_sq) {
  __shared__ float ls[DP], lq[DP];
  __shared__ int sptr[65];
  __shared__ __align__(16) int sidx[LDSE];
  int tid = threadIdx.x;
  for (int i = tid; i < DP; i += 256) { ls[i] = 0.f; lq[i] = 0.f; }
  int vb = blockIdx.x * 64;
  if (tid < 65) sptr[tid] = indptr[vb + tid];
  __syncthreads();
  int ebase = sptr[0];
  int ecnt = sptr[64] - ebase;
  const int* ip;
  if (ecnt <= LDSE) {
    for (int i = tid; i < ecnt; i += 256) sidx[i] = srcs[ebase + i];
    ip = sidx;
  } else {
    ip = srcs + ebase;
  }
  __syncthreads();

  int lane = tid & 63, wv = tid >> 6;
  int c0 = lane << 2;
  int lane2 = lane & 7;
  int c1 = 256 + (lane2 << 2);
  bool tl = lane < 16;
  bool loA = lane < 8;
  float bia[4], bib[4];
#pragma unroll
  for (int j = 0; j < 4; ++j) bia[j] = bias[c0 + j];
#pragma unroll
  for (int j = 0; j < 4; ++j) bib[j] = (tl && c1 + j < DIM) ? bias[c1 + j] : 0.f;
  float s0[4] = {}, q0[4] = {}, s1[4] = {}, q1[4] = {};

  for (int g = 0; g < 8; ++g) {
    int nA = wv * 16 + g;
    int nB = nA + 8;
    int ebA = sptr[nA] - ebase, neA = sptr[nA + 1] - sptr[nA];
    int ebB = sptr[nB] - ebase, neB = sptr[nB + 1] - sptr[nB];
    int nemax = neA > neB ? neA : neB;
    const u16* xA = X + (size_t)(vb + nA) * DP;
    const u16* xB = X + (size_t)(vb + nB) * DP;
    uint2 mA = *(const uint2*)(xA + c0);
    uint2 mB = *(const uint2*)(xB + c0);
    uint2 tS;
    if (tl) tS = *(const uint2*)((loA ? xA : xB) + c1);
    float A0[4] = {}, B0[4] = {}, C1[4] = {};
    acc4(A0, mA); acc4(B0, mB);
    if (tl) acc4(C1, tS);

    for (int e = 0; e < nemax; e += 4) {
      bool aA = e < neA, aB = e < neB;
      int oA = aA ? ebA + e : 0;
      int oB = aB ? ebB + e : 0;
      int4 i4a = *(const int4*)(ip + oA);
      int4 i4b = *(const int4*)(ip + oB);
      int ia[4], ib[4];
      ia[0] = aA ? i4a.x : NN; ia[1] = aA ? i4a.y : NN;
      ia[2] = aA ? i4a.z : NN; ia[3] = aA ? i4a.w : NN;
      ib[0] = aB ? i4b.x : NN; ib[1] = aB ? i4b.y : NN;
      ib[2] = aB ? i4b.z : NN; ib[3] = aB ? i4b.w : NN;
      const u16* pa[4]; const u16* pb[4];
#pragma unroll
      for (int j = 0; j < 4; ++j) {
        pa[j] = X + (size_t)ia[j] * DP;
        pb[j] = X + (size_t)ib[j] * DP;
      }
      uint2 ma[4], mb[4];
#pragma unroll
      for (int j = 0; j < 4; ++j) ma[j] = *(const uint2*)(pa[j] + c0);
#pragma unroll
      for (int j = 0; j < 4; ++j) mb[j] = *(const uint2*)(pb[j] + c0);
      uint2 tc[4];
      if (tl) {
#pragma unroll
        for (int j = 0; j < 4; ++j) tc[j] = *(const uint2*)((loA ? pa[j] : pb[j]) + c1);
      }
#pragma unroll
      for (int j = 0; j < 4; ++j) { acc4(A0, ma[j]); acc4(B0, mb[j]); }
      if (tl) {
#pragma unroll
        for (int j = 0; j < 4; ++j) acc4(C1, tc[j]);
      }
    }

    float dvA = dinv[vb + nA], dvB = dinv[vb + nB];
    u16* yA = Y + (size_t)(vb + nA) * DP;
    u16* yB = Y + (size_t)(vb + nB) * DP;
    float ya[4], yb[4];
#pragma unroll
    for (int j = 0; j < 4; ++j) {
      ya[j] = fmaf(dvA, A0[j], bia[j]);
      s0[j] += ya[j]; q0[j] += ya[j] * ya[j];
      yb[j] = fmaf(dvB, B0[j], bia[j]);
      s0[j] += yb[j]; q0[j] += yb[j] * yb[j];
    }
    uint2 wa, wb;
    wa.x = (unsigned)f2bf(ya[0]) | ((unsigned)f2bf(ya[1]) << 16);
    wa.y = (unsigned)f2bf(ya[2]) | ((unsigned)f2bf(ya[3]) << 16);
    wb.x = (unsigned)f2bf(yb[0]) | ((unsigned)f2bf(yb[1]) << 16);
    wb.y = (unsigned)f2bf(yb[2]) | ((unsigned)f2bf(yb[3]) << 16);
    *(uint2*)(yA + c0) = wa;
    *(uint2*)(yB + c0) = wb;
    if (tl) {
      float dvS = loA ? dvA : dvB;
      u16* yS = loA ? yA : yB;
      float z[4];
#pragma unroll
      for (int j = 0; j < 4; ++j) {
        z[j] = fmaf(dvS, C1[j], bib[j]);
        s1[j] += z[j]; q1[j] += z[j] * z[j];
      }
      uint2 w2;
      w2.x = (unsigned)f2bf(z[0]) | ((unsigned)f2bf(z[1]) << 16);
      w2.y = (unsigned)f2bf(z[2]) | ((unsigned)f2bf(z[3]) << 16);
      *(uint2*)(yS + c1) = w2;
    }
  }

#pragma unroll
  for (int j = 0; j < 4; ++j) { atomicAdd(&ls[c0 + j], s0[j]); atomicAdd(&lq[c0 + j], q0[j]); }
  if (tl) {
#pragma unroll
    for (int j = 0; j < 4; ++j) { atomicAdd(&ls[c1 + j], s1[j]); atomicAdd(&lq[c1 + j], q1[j]); }
  }
  __syncthreads();
  for (int i = tid; i < DP; i += 256) {
    atomicAdd(&bn_sum[i], ls[i]);
    atomicAdd(&bn_sq[i], lq[i]);
  }
}

// ---------------- MFMA Gram decode (r11) ----------------

__launch_bounds__(256)
__global__ void decode_kernel(const u16* __restrict__ H, float* __restrict__ out) {
  __shared__ __align__(16) u16 tile[4][2][NPG * BK];
  int tid = threadIdx.x, lane = tid & 63, wv = tid >> 6;
  int g = blockIdx.x * 4 + wv;
  const u16* Hg = H + (size_t)g * NPG * DP;
  const int ssl = lane & 3;
  int soff[4];
  const u16* sg[4];
#pragma unroll
  for (int i = 0; i < 4; ++i) {
    int r = (lane >> 2) + i * 16;
    soff[i] = r * BK + ((ssl ^ (r & 3) ^ ((r >> 2) & 3)) << 3);
    sg[i] = Hg + (size_t)r * DP + ssl * 8;
  }
  const int fr = lane & 15, fs = lane >> 4;
  const int fswz = ((fs ^ (fr & 3) ^ ((fr >> 2) & 3)) << 3);
  int foff[4];
#pragma unroll
  for (int i = 0; i < 4; ++i) foff[i] = (i * 16 + fr) * BK + fswz;

  u16* t0 = tile[wv][0];
  u16* t1 = tile[wv][1];
  uint4 rg[4];
#pragma unroll
  for (int i = 0; i < 4; ++i) rg[i] = *(const uint4*)(sg[i]);
#pragma unroll
  for (int i = 0; i < 4; ++i) *(uint4*)&t0[soff[i]] = rg[i];

  f32x4 acc[4][4];
#pragma unroll
  for (int i = 0; i < 4; ++i)
#pragma unroll
    for (int j = 0; j < 4; ++j) acc[i][j] = (f32x4){0.f, 0.f, 0.f, 0.f};

  for (int s = 0; s < DP / BK; ++s) {
    u16* cur = (s & 1) ? t1 : t0;
    u16* nxt = (s & 1) ? t0 : t1;
    const bool more = (s < DP / BK - 1);
    if (more) {
#pragma unroll
      for (int i = 0; i < 4; ++i) rg[i] = *(const uint4*)(sg[i] + (s + 1) * BK);
    }
    s16x8 af[4];
#pragma unroll
    for (int i = 0; i < 4; ++i) af[i] = *(const s16x8*)&cur[foff[i]];
#pragma unroll
    for (int i = 0; i < 4; ++i)
#pragma unroll
      for (int j = 0; j < 4; ++j)
        acc[i][j] = __builtin_amdgcn_mfma_f32_16x16x32_bf16(af[i], af[j], acc[i][j], 0, 0, 0);
    if (more) {
#pragma unroll
      for (int i = 0; i < 4; ++i) *(uint4*)&nxt[soff[i]] = rg[i];
    }
  }
  float* og = out + (size_t)g * NPG * NPG;
#pragma unroll
  for (int i = 0; i < 4; ++i) {
    int m0 = i * 16 + fs * 4;
#pragma unroll
    for (int j = 0; j < 4; ++j) {
      int n = j * 16 + fr;
#pragma unroll
      for (int r = 0; r < 4; ++r) og[(m0 + r) * NPG + n] = acc[i][j][r];
    }
  }
}

// ---------------- launch ----------------

extern "C" void kernel_launch(void* const* d_in, const int* in_sizes, int n_in,
                              void* d_out, int out_size, void* d_ws, size_t ws_size,
                              hipStream_t stream) {
  const int* xa = (const int*)d_in[0];
  const int* ei = (const int*)d_in[1];
  const float* emb = (const float*)d_in[2];
  const float* convW = (const float*)d_in[3];
  const float* convB = (const float*)d_in[4];
  const float* gamma = (const float*)d_in[5];
  const float* beta = (const float*)d_in[6];
  const float* postW = (const float*)d_in[7];
  const float* postB = (const float*)d_in[8];
  float* out = (float*)d_out;

  char* w = (char*)d_ws;
  u16* P = (u16*)w;          w += (size_t)(NN + 1) * DP * sizeof(u16);
  u16* Q = (u16*)w;          w += (size_t)(NN + 1) * DP * sizeof(u16);
  u16* Wr = (u16*)w;         w += (size_t)6 * WELEM * sizeof(u16);
  float* dinv = (float*)w;   w += (size_t)NN * sizeof(float);
  int* cnt = (int*)w;        w += (size_t)NN * sizeof(int);
  int* cnt_pad = (int*)w;    w += (size_t)NN * sizeof(int);
  int* indptr = (int*)w;     w += (size_t)(NN + 64) * sizeof(int);
  int* cursor = (int*)w;     w += (size_t)NN * sizeof(int);
  int* srcs = (int*)w;       w += (size_t)NEPAD * sizeof(int);
  int* partials = (int*)w;   w += 256 * sizeof(int);
  float* bnstats = (float*)w; w += (size_t)NLAY * 2 * DP * sizeof(float);

  size_t need = (size_t)(w - (char*)d_ws);
  if (ws_size < need) return;

  hipMemsetAsync(cnt, 0, (size_t)NN * sizeof(int), stream);
  hipMemsetAsync(bnstats, 0, (size_t)NLAY * 2 * DP * sizeof(float), stream);
  hist_kernel<<<NE / 256, 256, 0, stream>>>(ei, cnt);
  pad_dinv_kernel<<<NN / 256, 256, 0, stream>>>(cnt, cnt_pad, dinv);
  scan_block_kernel<<<NN / 1024, 1024, 0, stream>>>(cnt_pad, indptr, partials);
  scan_partials_kernel<<<1, 128, 0, stream>>>(partials);
  add_offsets_kernel<<<NN / 256, 256, 0, stream>>>(indptr, partials, cursor, cnt_pad);
  fill_csr_kernel<<<NE / 256, 256, 0, stream>>>(ei, cursor, srcs);
  pad_fill_kernel<<<NN / 256, 256, 0, stream>>>(cursor, indptr, srcs);
  wpad_kernel<<<(6 * WELEM + 255) / 256, 256, 0, stream>>>(convW, postW, Wr);
  embed_kernel<<<NN, 128, 0, stream>>>(xa, emb, P);
  zrow_kernel<<<1, 288, 0, stream>>>(P, Q);

  for (int l = 0; l < NLAY; ++l) {
    const float* bs = l ? bnstats + (size_t)(l - 1) * 2 * DP : nullptr;
    gemm_kernel<<<NN / 64, 256, 0, stream>>>(
        P, Wr + (size_t)l * WELEM, Q,
        bs, bs ? bs + DP : nullptr,
        l ? gamma + (size_t)(l - 1) * DIM : nullptr,
        l ? beta + (size_t)(l - 1) * DIM : nullptr,
        dinv, nullptr);
    spmm_kernel<<<NN / 64, 256, 0, stream>>>(Q, P, indptr, srcs, dinv,
                                             convB + (size_t)l * DIM,
                                             bnstats + (size_t)l * 2 * DP,
                                             bnstats + (size_t)l * 2 * DP + DP);
  }

  const float* bs5 = bnstats + (size_t)4 * 2 * DP;
  gemm_kernel<<<NN / 64, 256, 0, stream>>>(
      P, Wr + (size_t)5 * WELEM, Q, bs5, bs5 + DP,
      gamma + (size_t)4 * DIM, beta + (size_t)4 * DIM, nullptr, postB);

  decode_kernel<<<NGRAPH / 4, 256, 0, stream>>>(Q, out);
}